// Round 5
// baseline (248.011 us; speedup 1.0000x reference)
//
#include <hip/hip_runtime.h>
#include <hip/hip_bf16.h>

typedef __attribute__((ext_vector_type(8))) short short8;
typedef __attribute__((ext_vector_type(4))) float floatx4;
typedef __attribute__((ext_vector_type(16))) float floatx16;

#define N_ROWS 32768
#define D_DIM  128
#define H_KEYS 8192
#define C_COLS 100
#define LOG2E  1.4426950408889634f

// workspace layout (total 3,964,928 B — proven footprint)
#define KP_BYTES  (H_KEYS * D_DIM * 2)        // 2,097,152: K packed, 32x32x16 A-frag order
#define VP_BYTES  (512 * 3584)                // 1,835,008: V packed 112-col units
#define KSQ_OFF   (KP_BYTES + VP_BYTES)       // 3,932,160: ksq in D-reg order, 32 KB

// v_cvt_pk_bf16_f32: two fp32 -> packed bf16 (a low, b high)
__device__ __forceinline__ unsigned int pk2bf(float a, float b) {
  union { __hip_bfloat162 h; unsigned int u; } c;
  c.h = __float22bfloat162_rn(float2{a, b});
  return c.u;
}

// async global->LDS; global addr per-lane, LDS dest = wave-uniform base + lane*width
__device__ __forceinline__ void glds16(const void* g, void* l) {
  __builtin_amdgcn_global_load_lds(
      (const __attribute__((address_space(1))) unsigned int*)g,
      (__attribute__((address_space(3))) unsigned int*)l, 16, 0, 0);
}
__device__ __forceinline__ void glds4(const void* g, void* l) {
  __builtin_amdgcn_global_load_lds(
      (const __attribute__((address_space(1))) unsigned int*)g,
      (__attribute__((address_space(3))) unsigned int*)l, 4, 0, 0);
}

// ---------------------------------------------------------------------------
// pack_k32: K [8192x128] fp32 -> 32x32x16 MFMA A-fragment order, scaled by
// 2*log2e/T; also emits ksqp[kt][hh][reg] = -|k|^2*log2e/T in the exact
// C/D-register order of the 32x32 tile (key = (reg&3)+8*(reg>>2)+4*hh).
// (verbatim harness-verified round-3 version)
// ---------------------------------------------------------------------------
__global__ __launch_bounds__(256) void pack_k32(const float* __restrict__ keys,
                                                const float* __restrict__ temp,
                                                unsigned short* __restrict__ kp,
                                                float* __restrict__ ksqp) {
  __shared__ __align__(16) float kt_lds[32 * 132];
  __shared__ float aux[32 * 8];
  __shared__ float ssq[32];
  const int kt = blockIdx.x;
  const int t = threadIdx.x;
  const float* src = keys + (size_t)kt * 4096;
#pragma unroll
  for (int i = 0; i < 4; ++i) {
    int idx = i * 1024 + t * 4;
    float4 v = *(const float4*)(src + idx);
    int row = idx >> 7, col = idx & 127;
    *(float4*)(&kt_lds[row * 132 + col]) = v;
  }
  __syncthreads();
  {
    int row = t >> 3, seg = t & 7;
    const float* p = &kt_lds[row * 132 + seg * 16];
    float s = 0.f;
#pragma unroll
    for (int j = 0; j < 16; ++j) s += p[j] * p[j];
    aux[row * 8 + seg] = s;
  }
  __syncthreads();
  const float tv = temp[0];
  if (t < 32) {
    float s = 0.f;
#pragma unroll
    for (int j = 0; j < 8; ++j) s += aux[t * 8 + j];
    ssq[t] = s;
  }
  __syncthreads();
  if (t < 32) {
    int h = t >> 4, reg = t & 15;
    int key = (reg & 3) + 8 * (reg >> 2) + 4 * h;
    ksqp[((size_t)kt * 2 + h) * 16 + reg] = -ssq[key] * LOG2E / tv;
  }
  const float kscale = 2.0f * LOG2E / tv;
#pragma unroll
  for (int u0 = 0; u0 < 2; ++u0) {
    int u = t + u0 * 256;            // 512 tasks: 8 dc x 64 lanes
    int dc = u >> 6, l = u & 63;
    const float* p = &kt_lds[(l & 31) * 132 + dc * 16 + (l >> 5) * 8];
    union { short8 v; unsigned int ui[4]; } cv;
#pragma unroll
    for (int j = 0; j < 4; ++j)
      cv.ui[j] = pk2bf(p[2 * j] * kscale, p[2 * j + 1] * kscale);
    *(short8*)(kp + ((size_t)(kt * 8 + dc) * 64 + l) * 8) = cv.v;
  }
}

// ---------------------------------------------------------------------------
// pack_v32: V [8192x100] -> 32x32x16 B-frag units of 3584 B per (32-key b,
// 16-key kc): nt 0..2 full 32-col tiles + nt 3 half-tile (cols 96..111;
// col 100 = 1.0 -> denominator). (verbatim harness-verified round-3 version)
// ---------------------------------------------------------------------------
__global__ __launch_bounds__(256) void pack_v32(const float* __restrict__ values,
                                                unsigned short* __restrict__ vp) {
  __shared__ float vt[32 * 104];
  const int b = blockIdx.x;        // keys [32b, 32b+32)
  const int t = threadIdx.x;
  const float* src = values + (size_t)b * 32 * C_COLS;
  for (int idx = t; idx < 32 * C_COLS; idx += 256) {
    int row = idx / C_COLS, col = idx - row * C_COLS;
    vt[row * 104 + col] = src[idx];
  }
  __syncthreads();
  unsigned short* dst = vp + (size_t)b * 2 * 1792;   // 2 units of 1792 ushorts
#pragma unroll
  for (int u0 = 0; u0 < 2; ++u0) {
    int u = t + u0 * 256;            // 448 tasks: 384 full-tile + 64 half-tile
    if (u < 384) {
      int kc = u / 192, rem = u - kc * 192;
      int nt = rem >> 6, l = rem & 63;
      int col = nt * 32 + (l & 31);
      int k0 = kc * 16 + (l >> 5) * 8;
      union { short8 v; unsigned int ui[4]; } cv;
#pragma unroll
      for (int j = 0; j < 4; ++j)
        cv.ui[j] = pk2bf(vt[(k0 + 2 * j) * 104 + col], vt[(k0 + 2 * j + 1) * 104 + col]);
      *(short8*)(dst + kc * 1792 + nt * 512 + l * 8) = cv.v;
    } else if (u < 448) {
      int v = u - 384;               // 0..63
      int kc = v >> 5, slot = v & 31;
      int hh = slot >> 4, c16 = slot & 15;
      int col = 96 + c16;
      int k0 = kc * 16 + hh * 8;
      union { short8 v8; unsigned int ui[4]; } cv;
#pragma unroll
      for (int j = 0; j < 4; ++j) {
        float a  = (col < C_COLS) ? vt[(k0 + 2 * j) * 104 + col]
                                  : (col == C_COLS ? 1.0f : 0.0f);
        float bb = (col < C_COLS) ? vt[(k0 + 2 * j + 1) * 104 + col]
                                  : (col == C_COLS ? 1.0f : 0.0f);
        cv.ui[j] = pk2bf(a, bb);
      }
      *(short8*)(dst + kc * 1792 + 1536 + slot * 8) = cv.v8;
    }
  }
}

// ---------------------------------------------------------------------------
// attn_rbf32: verified round-3 structure (stage(it+1) -> QKT(it) -> pack ->
// PV(it) -> barrier), plus three safe latency fixes:
//  (1) ksq bias prefetched one iteration ahead into registers (kqA/kqB,
//      even/odd hand-unroll) — removes L2 stall at QKT chain head;
//  (2) QKT split into two interleaved 4-MFMA chains (a0 bias-init, a1 zero,
//      fused add in exp2 input) — halves dependency-chain depth;
//  (3) s_setprio(1) around QKT and PV MFMA clusters (T5).
// Block = 256 threads (4 waves) = 64 x-rows; wave (s,t): s = row slice,
// t = key tile. Grid 512 -> 2 blocks/CU.
// ---------------------------------------------------------------------------
__global__ __launch_bounds__(256, 2)
void attn_rbf32(const float* __restrict__ x,
                const unsigned short* __restrict__ kp,
                const unsigned short* __restrict__ vp,
                const float* __restrict__ ksqp,
                float* __restrict__ out) {
  __shared__ __align__(16) char smem[61440];  // K: 2x16384 @0 | V: 2x14336 @32768
  const int tid = threadIdx.x;
  const int w = tid >> 6;
  const int lane = tid & 63;
  const int l31 = lane & 31;
  const int hh = lane >> 5;            // lane half (key sub-group)
  const int s = w >> 1;                // x-row slice 0/1
  const int t = w & 1;                 // key tile within pair
  const int rb = blockIdx.x;           // rows [64rb, 64rb+64)

  // X B-fragments for this wave's 32 rows: xf[dc][j] = X[row][dc*16+hh*8+j]
  short8 xf[8];
  {
    const float* xr = x + ((size_t)rb * 64 + s * 32 + l31) * D_DIM + hh * 8;
#pragma unroll
    for (int dc = 0; dc < 8; ++dc) {
      float4 lo = *(const float4*)(xr + dc * 16);
      float4 hi = *(const float4*)(xr + dc * 16 + 4);
      union { short8 v; unsigned int ui[4]; } cv;
      cv.ui[0] = pk2bf(lo.x, lo.y); cv.ui[1] = pk2bf(lo.z, lo.w);
      cv.ui[2] = pk2bf(hi.x, hi.y); cv.ui[3] = pk2bf(hi.z, hi.w);
      xf[dc] = cv.v;
    }
  }

  floatx16 oacc[4];
#pragma unroll
  for (int nt = 0; nt < 4; ++nt) oacc[nt] = (floatx16)0.0f;

  const char* kpg = (const char*)kp;
  const char* vpg = (const char*)vp;

#define STAGE_KV(ITN) do {                                                   \
    const char* gk_ = kpg + (size_t)(ITN) * 16384 + w * 4096;                \
    char* lk_ = smem + (((ITN) & 1) * 16384) + w * 4096;                     \
    glds16(gk_ + lane * 16, lk_);                                            \
    glds16(gk_ + 1024 + lane * 16, lk_ + 1024);                              \
    glds16(gk_ + 2048 + lane * 16, lk_ + 2048);                              \
    glds16(gk_ + 3072 + lane * 16, lk_ + 3072);                              \
    const char* gv_ = vpg + (size_t)(ITN) * 14336 + w * 3584;                \
    char* lv_ = smem + 32768 + (((ITN) & 1) * 14336) + w * 3584;             \
    glds16(gv_ + lane * 16, lv_);                                            \
    glds16(gv_ + 1024 + lane * 16, lv_ + 1024);                              \
    glds16(gv_ + 2048 + lane * 16, lv_ + 2048);                              \
    glds4(gv_ + 3072 + lane * 4, lv_ + 3072);                                \
    glds4(gv_ + 3328 + lane * 4, lv_ + 3328);                                \
  } while (0)

#define KQ_LOAD(KQ, ITQ) do {                                                \
    const floatx4* kq_ =                                                     \
        (const floatx4*)(ksqp + (((size_t)(2 * (ITQ) + t)) * 2 + hh) * 16);  \
    KQ[0] = kq_[0]; KQ[1] = kq_[1]; KQ[2] = kq_[2]; KQ[3] = kq_[3];          \
  } while (0)

  // full iteration: QKT(it) (two interleaved 4-chains) -> pack -> PV(it)
#define ITER_COMPUTE(IT, KQ) do {                                            \
    floatx16 a0_, a1_;                                                       \
    a0_[0]  = KQ[0][0]; a0_[1]  = KQ[0][1]; a0_[2]  = KQ[0][2]; a0_[3]  = KQ[0][3]; \
    a0_[4]  = KQ[1][0]; a0_[5]  = KQ[1][1]; a0_[6]  = KQ[1][2]; a0_[7]  = KQ[1][3]; \
    a0_[8]  = KQ[2][0]; a0_[9]  = KQ[2][1]; a0_[10] = KQ[2][2]; a0_[11] = KQ[2][3]; \
    a0_[12] = KQ[3][0]; a0_[13] = KQ[3][1]; a0_[14] = KQ[3][2]; a0_[15] = KQ[3][3]; \
    a1_ = (floatx16)0.0f;                                                    \
    const char* Kb_ = smem + (((IT) & 1) * 16384) + t * 8192;                \
    __builtin_amdgcn_s_setprio(1);                                           \
    _Pragma("unroll")                                                        \
    for (int dc = 0; dc < 4; ++dc) {                                         \
      short8 kf0_ = *(const short8*)(Kb_ + dc * 1024 + lane * 16);           \
      short8 kf1_ = *(const short8*)(Kb_ + (dc + 4) * 1024 + lane * 16);     \
      a0_ = __builtin_amdgcn_mfma_f32_32x32x16_bf16(kf0_, xf[dc], a0_, 0, 0, 0); \
      a1_ = __builtin_amdgcn_mfma_f32_32x32x16_bf16(kf1_, xf[dc + 4], a1_, 0, 0, 0); \
    }                                                                        \
    __builtin_amdgcn_s_setprio(0);                                           \
    unsigned int pr_[8];                                                     \
    _Pragma("unroll")                                                        \
    for (int j = 0; j < 8; ++j)                                              \
      pr_[j] = pk2bf(__builtin_amdgcn_exp2f(a0_[2 * j] + a1_[2 * j]),        \
                     __builtin_amdgcn_exp2f(a0_[2 * j + 1] + a1_[2 * j + 1])); \
    asm("v_permlane32_swap_b32 %0, %1" : "+v"(pr_[0]), "+v"(pr_[2]));        \
    asm("v_permlane32_swap_b32 %0, %1" : "+v"(pr_[1]), "+v"(pr_[3]));        \
    asm("v_permlane32_swap_b32 %0, %1" : "+v"(pr_[4]), "+v"(pr_[6]));        \
    asm("v_permlane32_swap_b32 %0, %1" : "+v"(pr_[5]), "+v"(pr_[7]));        \
    short8 paf_[2];                                                          \
    {                                                                        \
      union { short8 v; unsigned int ui[4]; } c0_, c1_;                      \
      c0_.ui[0] = pr_[0]; c0_.ui[1] = pr_[1]; c0_.ui[2] = pr_[2]; c0_.ui[3] = pr_[3]; \
      c1_.ui[0] = pr_[4]; c1_.ui[1] = pr_[5]; c1_.ui[2] = pr_[6]; c1_.ui[3] = pr_[7]; \
      paf_[0] = c0_.v; paf_[1] = c1_.v;                                      \
    }                                                                        \
    const char* Vb_ = smem + 32768 + (((IT) & 1) * 14336) + t * 7168;        \
    __builtin_amdgcn_s_setprio(1);                                           \
    _Pragma("unroll")                                                        \
    for (int kc = 0; kc < 2; ++kc) {                                         \
      const char* unit_ = Vb_ + kc * 3584;                                   \
      _Pragma("unroll")                                                      \
      for (int nt = 0; nt < 3; ++nt) {                                       \
        short8 vf_ = *(const short8*)(unit_ + nt * 1024 + lane * 16);        \
        oacc[nt] = __builtin_amdgcn_mfma_f32_32x32x16_bf16(paf_[kc], vf_, oacc[nt], 0, 0, 0); \
      }                                                                      \
      short8 vf3_ = *(const short8*)(unit_ + 3072 + (hh * 16 + (l31 & 15)) * 16); \
      if (l31 >= 16) vf3_ = (short8)0;                                       \
      oacc[3] = __builtin_amdgcn_mfma_f32_32x32x16_bf16(paf_[kc], vf3_, oacc[3], 0, 0, 0); \
    }                                                                        \
    __builtin_amdgcn_s_setprio(0);                                           \
  } while (0)

  floatx4 kqA[4], kqB[4];

  // prologue: stage iter 0 into parity 0; preload bias(0)
  STAGE_KV(0);
  KQ_LOAD(kqA, 0);
  __syncthreads();

#pragma unroll 1
  for (int base = 0; base < 128; base += 2) {
    // ---- even iteration: uses kqA; prefetches bias(base+1) -> kqB ----
    {
      const int it = base;
      if (it < 127) STAGE_KV(it + 1);
      KQ_LOAD(kqB, it + 1);            // it+1 <= 127 always for even it
      ITER_COMPUTE(it, kqA);
      __syncthreads();                 // stage(it+1) landed; bufs(it) free
    }
    // ---- odd iteration: uses kqB; prefetches bias(base+2) -> kqA ----
    {
      const int it = base + 1;
      if (it < 127) {
        STAGE_KV(it + 1);
        KQ_LOAD(kqA, it + 1);
      }
      ITER_COMPUTE(it, kqB);
      __syncthreads();
    }
  }

#undef ITER_COMPUTE
#undef KQ_LOAD
#undef STAGE_KV

  // ---- epilogue: combine key-tile partials (t=0/1) in LDS, normalize ----
  float* OL = (float*)smem;            // [64][105] fp32 = 26880 B (K region)
  const int OLS = 105;
  float* rden = (float*)(smem + 26880);   // 64 floats
  if (t == 0) {
#pragma unroll
    for (int nt = 0; nt < 4; ++nt) {
      int col = nt * 32 + l31;
      if (col <= C_COLS) {
#pragma unroll
        for (int r = 0; r < 16; ++r) {
          int row = s * 32 + (r & 3) + 8 * (r >> 2) + 4 * hh;
          OL[row * OLS + col] = oacc[nt][r];
        }
      }
    }
  }
  __syncthreads();
  if (t == 1) {
#pragma unroll
    for (int nt = 0; nt < 4; ++nt) {
      int col = nt * 32 + l31;
      if (col <= C_COLS) {
#pragma unroll
        for (int r = 0; r < 16; ++r) {
          int row = s * 32 + (r & 3) + 8 * (r >> 2) + 4 * hh;
          OL[row * OLS + col] += oacc[nt][r];
        }
      }
    }
  }
  __syncthreads();
  if (tid < 64) rden[tid] = 1.0f / OL[tid * OLS + C_COLS];
  __syncthreads();
  float* outb = out + (size_t)rb * (64 * C_COLS);
  for (int idx = tid; idx < 64 * C_COLS; idx += 256) {
    int r = idx / C_COLS;
    int c = idx - r * C_COLS;
    outb[idx] = OL[r * OLS + c] * rden[r];
  }
}

extern "C" void kernel_launch(void* const* d_in, const int* in_sizes, int n_in,
                              void* d_out, int out_size, void* d_ws, size_t ws_size,
                              hipStream_t stream) {
  (void)in_sizes; (void)n_in; (void)out_size; (void)ws_size;
  const float* x      = (const float*)d_in[0];
  const float* keys   = (const float*)d_in[1];
  const float* values = (const float*)d_in[2];
  const float* temp   = (const float*)d_in[3];
  float* out = (float*)d_out;

  char* ws = (char*)d_ws;
  unsigned short* kp   = (unsigned short*)(ws);
  unsigned short* vp   = (unsigned short*)(ws + KP_BYTES);
  float*          ksqp = (float*)(ws + KSQ_OFF);

  hipLaunchKernelGGL(pack_k32,   dim3(256), dim3(256), 0, stream, keys, temp, kp, ksqp);
  hipLaunchKernelGGL(pack_v32,   dim3(256), dim3(256), 0, stream, values, vp);
  hipLaunchKernelGGL(attn_rbf32, dim3(512), dim3(256), 0, stream, x, kp, vp, ksqp, out);
}

// Round 6
// 204.113 us; speedup vs baseline: 1.2151x; 1.2151x over previous
//
#include <hip/hip_runtime.h>
#include <hip/hip_bf16.h>

typedef __attribute__((ext_vector_type(8))) short short8;
typedef __attribute__((ext_vector_type(4))) float floatx4;

#define N_ROWS 32768
#define D_DIM  128
#define H_KEYS 8192
#define C_COLS 100
#define BM     64
#define BH     128
#define P_STRIDE  136   // ushorts per P row (272 B, 16B-aligned rows)
#define P_BYTES   (BM * P_STRIDE * 2)   // 17408 B per buffer
#define OL_STRIDE 113   // floats per OL row (odd -> conflict-free epilogue)
#define LOG2E 1.4426950408889634f

__device__ __forceinline__ unsigned short f2bf(float f) {
  union { float f; unsigned int u; } v; v.f = f;
  unsigned int r = v.u + 0x7fffu + ((v.u >> 16) & 1u);  // RNE
  return (unsigned short)(r >> 16);
}

// v_cvt_pk_bf16_f32: two fp32 -> packed bf16 (a in low 16, b in high 16)
__device__ __forceinline__ unsigned int pk2bf(float a, float b) {
  union { __hip_bfloat162 h; unsigned int u; } c;
  c.h = __float22bfloat162_rn(float2{a, b});
  return c.u;
}

// ---------------------------------------------------------------------------
// pack_all: single-launch fusion of the three (harness-verified, logic
// verbatim) preprocessing kernels.
//   blocks [0,512):    pack_k — K fp32 -> MFMA A-frag order, scaled 2*log2e/T
//   blocks [512,768):  pack_v — V -> PV B-frag order, 112 cols, ones at 100
//   blocks [768,2816): ksq    — ksq[h] = -|k_h|^2 * log2e / T (1 wave/key)
// Fusion removes 2 kernel-launch boundaries (~measured 64.7us total-minus-attn
// gap for 4 launches).
// ---------------------------------------------------------------------------
__global__ __launch_bounds__(256) void pack_all(const float* __restrict__ keys,
                                                const float* __restrict__ values,
                                                const float* __restrict__ temp,
                                                unsigned short* __restrict__ kp,
                                                unsigned short* __restrict__ vp,
                                                float* __restrict__ ksq) {
  const int bid = blockIdx.x;
  if (bid < 512) {
    // ---- pack_k (verbatim round-0 logic) ----
    int gid = bid * 256 + threadIdx.x;
    int lane = gid & 63;
    int c = (gid >> 6) & 3;
    int rt = gid >> 8;
    float scale = 2.0f * LOG2E / temp[0];
    int row = rt * 16 + (lane & 15);
    int d0 = c * 32 + (lane >> 4) * 8;
    const float* s = keys + (size_t)row * D_DIM + d0;
    short8 o;
#pragma unroll
    for (int j = 0; j < 8; ++j) o[j] = (short)f2bf(s[j] * scale);
    *(short8*)(kp + (size_t)gid * 8) = o;
  } else if (bid < 768) {
    // ---- pack_v (verbatim round-0 logic) ----
    __shared__ float vt[32 * 113];
    int g = bid - 512;
    int tid = threadIdx.x;
    for (int idx = tid; idx < 32 * 112; idx += 256) {
      int k = idx / 112, col = idx - k * 112;
      float val;
      if (col < C_COLS) val = values[(size_t)(g * 32 + k) * C_COLS + col];
      else val = (col == C_COLS) ? 1.0f : 0.0f;
      vt[k * 113 + col] = val;
    }
    __syncthreads();
    for (int u = tid; u < 7 * 64; u += 256) {
      int ct = u >> 6, l = u & 63;
      int n0 = l & 15, q = l >> 4;
      short8 o;
#pragma unroll
      for (int j = 0; j < 8; ++j) o[j] = (short)f2bf(vt[(q * 8 + j) * 113 + ct * 16 + n0]);
      *(short8*)(vp + ((size_t)(g * 7 + ct) * 64 + l) * 8) = o;
    }
  } else {
    // ---- ksq (verbatim round-0 logic; one wave per key) ----
    int wid = ((bid - 768) * 256 + threadIdx.x) >> 6;  // key index
    int lane = threadIdx.x & 63;
    const float2* row = (const float2*)(keys + (size_t)wid * D_DIM);
    float2 v = row[lane];
    float s = v.x * v.x + v.y * v.y;
#pragma unroll
    for (int off = 32; off > 0; off >>= 1) s += __shfl_down(s, off);
    if (lane == 0) ksq[wid] = -s * LOG2E / temp[0];
  }
}

// ---------------------------------------------------------------------------
// attn_rbf_kernel: VERBATIM the harness-verified 139.5us kernel (round-0).
// S^T = Kscaled.X^T with C initialized to -ksq*log2e/T, P = exp2(S) in bf16
// -> LDS (double-buffered, 1 barrier/iter), O += P.V.  4 blocks/CU,
// 4 waves/SIMD (the occupancy the register-P redesign could not reach).
// ---------------------------------------------------------------------------
__global__ __launch_bounds__(256, 2)
void attn_rbf_kernel(const float* __restrict__ x,
                     const unsigned short* __restrict__ kp,
                     const float* __restrict__ ksq,
                     const unsigned short* __restrict__ vp,
                     float* __restrict__ out) {
  __shared__ __align__(16) char smem[2 * P_BYTES];  // 34816 B; epilogue OL aliases front
  float* OL = (float*)smem;
  float* rden = (float*)(smem + BM * OL_STRIDE * 4);  // 64 floats at +28928

  const int tid = threadIdx.x;
  const int w = tid >> 6;       // wave 0..3
  const int lane = tid & 63;
  const int n0 = lane & 15;
  const int q = lane >> 4;
  const int b = blockIdx.x;     // row block: rows [64b, 64b+64)

  // Load x rows for this block directly (fp32 row-major), convert to B-fragments.
  short8 xf[4][4];
#pragma unroll
  for (int rt = 0; rt < 4; ++rt)
#pragma unroll
    for (int c = 0; c < 4; ++c) {
      const float* s = x + (size_t)(b * 64 + rt * 16 + n0) * D_DIM + c * 32 + q * 8;
      float4 lo = *(const float4*)s;
      float4 hi = *(const float4*)(s + 4);
      union { short8 v; unsigned int u[4]; } cv;
      cv.u[0] = pk2bf(lo.x, lo.y);
      cv.u[1] = pk2bf(lo.z, lo.w);
      cv.u[2] = pk2bf(hi.x, hi.y);
      cv.u[3] = pk2bf(hi.z, hi.w);
      xf[rt][c] = cv.v;
    }

  floatx4 oacc[4][2];
#pragma unroll
  for (int rt = 0; rt < 4; ++rt)
#pragma unroll
    for (int u = 0; u < 2; ++u)
      oacc[rt][u] = (floatx4){0.f, 0.f, 0.f, 0.f};

  const int nct = (w < 3) ? 2 : 1;  // waves own C-tiles {0,1},{2,3},{4,5},{6}
  const int ct0 = w * 2;

  for (int it = 0; it < H_KEYS / BH; ++it) {
    unsigned short* P = (unsigned short*)(smem + (it & 1) * P_BYTES);

    // ---- global prefetch (L2-resident streams) ----
    short8 kf[2][4];
#pragma unroll
    for (int kt = 0; kt < 2; ++kt)
#pragma unroll
      for (int c = 0; c < 4; ++c)
        kf[kt][c] = *(const short8*)(kp + ((size_t)((it * 8 + w * 2 + kt) * 4 + c) * 64 + lane) * 8);

    floatx4 ksq4[2];
#pragma unroll
    for (int kt = 0; kt < 2; ++kt)
      ksq4[kt] = *(const floatx4*)(ksq + it * BH + w * 32 + kt * 16 + q * 4);

    short8 vf[4][2];
#pragma unroll
    for (int c = 0; c < 4; ++c)
#pragma unroll
      for (int u = 0; u < 2; ++u)
        if (u < nct)
          vf[c][u] = *(const short8*)(vp + ((size_t)((it * 4 + c) * 7 + (ct0 + u)) * 64 + lane) * 8);

    // ---- S^T = K . X^T, C initialized to -ksq (folded softmax bias) ----
#pragma unroll
    for (int kt = 0; kt < 2; ++kt) {
      floatx4 s[4];
#pragma unroll
      for (int rt = 0; rt < 4; ++rt) s[rt] = ksq4[kt];
#pragma unroll
      for (int c = 0; c < 4; ++c)
#pragma unroll
        for (int rt = 0; rt < 4; ++rt)
          s[rt] = __builtin_amdgcn_mfma_f32_16x16x32_bf16(kf[kt][c], xf[rt][c], s[rt], 0, 0, 0);
      // exp2 + packed cvt: 4 keys -> one ds_write_b64
#pragma unroll
      for (int rt = 0; rt < 4; ++rt) {
        uint2 pk;
        pk.x = pk2bf(__builtin_amdgcn_exp2f(s[rt][0]), __builtin_amdgcn_exp2f(s[rt][1]));
        pk.y = pk2bf(__builtin_amdgcn_exp2f(s[rt][2]), __builtin_amdgcn_exp2f(s[rt][3]));
        *(uint2*)(P + (rt * 16 + n0) * P_STRIDE + w * 32 + kt * 16 + q * 4) = pk;
      }
    }
    __syncthreads();  // single barrier: P complete; next iter writes the other buffer

    // ---- O += P . V (wave w owns its C-tiles, all 64 rows) ----
#pragma unroll
    for (int c = 0; c < 4; ++c) {
      short8 pf[4];
#pragma unroll
      for (int rt = 0; rt < 4; ++rt)
        pf[rt] = *(const short8*)(P + (rt * 16 + n0) * P_STRIDE + c * 32 + q * 8);
#pragma unroll
      for (int u = 0; u < 2; ++u)
        if (u < nct)
#pragma unroll
          for (int rt = 0; rt < 4; ++rt)
            oacc[rt][u] = __builtin_amdgcn_mfma_f32_16x16x32_bf16(pf[rt], vf[c][u], oacc[rt][u], 0, 0, 0);
    }
  }
  __syncthreads();  // all waves done reading P before OL overlays it

  // ---- epilogue: O tiles -> LDS fp32, per-row reciprocal, coalesced store ----
#pragma unroll
  for (int rt = 0; rt < 4; ++rt)
#pragma unroll
    for (int u = 0; u < 2; ++u)
      if (u < nct)
#pragma unroll
        for (int i = 0; i < 4; ++i)
          OL[(rt * 16 + q * 4 + i) * OL_STRIDE + (ct0 + u) * 16 + n0] = oacc[rt][u][i];
  __syncthreads();
  if (tid < BM) rden[tid] = 1.0f / OL[tid * OL_STRIDE + 100];
  __syncthreads();

  float* outb = out + (size_t)b * (BM * C_COLS);
  for (int idx = tid; idx < BM * C_COLS; idx += 256) {
    int n = idx / C_COLS;
    int cc = idx - n * C_COLS;
    outb[idx] = OL[n * OL_STRIDE + cc] * rden[n];
  }
}

extern "C" void kernel_launch(void* const* d_in, const int* in_sizes, int n_in,
                              void* d_out, int out_size, void* d_ws, size_t ws_size,
                              hipStream_t stream) {
  (void)in_sizes; (void)n_in; (void)out_size; (void)ws_size;
  const float* x      = (const float*)d_in[0];
  const float* keys   = (const float*)d_in[1];
  const float* values = (const float*)d_in[2];
  const float* temp   = (const float*)d_in[3];
  float* out = (float*)d_out;

  char* ws = (char*)d_ws;
  unsigned short* kp  = (unsigned short*)(ws);             // 8192*128*2 = 2097152 B
  unsigned short* vp  = (unsigned short*)(ws + 2097152);   // 8192*112*2 = 1835008 B
  float*          ksq = (float*)(ws + 3932160);            // 8192*4     = 32768 B

  hipLaunchKernelGGL(pack_all,        dim3(2816), dim3(256), 0, stream,
                     keys, values, temp, kp, vp, ksq);
  hipLaunchKernelGGL(attn_rbf_kernel, dim3(512),  dim3(256), 0, stream, x, kp, ksq, vp, out);
}